// Round 4
// baseline (214.831 us; speedup 1.0000x reference)
//
#include <hip/hip_runtime.h>
#include <stdint.h>
#include <math.h>

#define SEQ 4096
#define DM  1024
#define NH  16
#define DH  64
#define LOG2E 1.44269504088896341f

typedef short bf16x8 __attribute__((ext_vector_type(8)));
typedef short bf16x4 __attribute__((ext_vector_type(4)));
typedef float f32x4  __attribute__((ext_vector_type(4)));
typedef uint32_t u32x4 __attribute__((ext_vector_type(4)));

typedef const __attribute__((address_space(1))) short* gptr_t;
typedef __attribute__((address_space(3))) short* lptr_t;

__device__ __forceinline__ short f2bf(float f) {
    union { float f; uint32_t u; } x; x.f = f;
    uint32_t r = (x.u + 0x7fffu + ((x.u >> 16) & 1u)) >> 16;
    return (short)r;
}
// pack two f32 -> dword of two bf16 (RNE), lo in low half — 1 VALU op
__device__ __forceinline__ uint32_t cvtpk(float lo, float hi) {
    uint32_t r;
    asm("v_cvt_pk_bf16_f32 %0, %1, %2" : "=v"(r) : "v"(lo), "v"(hi));
    return r;
}

__device__ __forceinline__ void load_lds16(const short* g, const short* l) {
    __builtin_amdgcn_global_load_lds((gptr_t)(uintptr_t)g,
                                     (lptr_t)(uint32_t)(uintptr_t)l, 16, 0, 0);
}

// ---- fused prep: blocks [0,2048) convert x fp32->bf16; blocks [2048,2816)
//      transpose w [1024][3072] -> wtb [3072][1024] bf16, Q cols pre-scaled ----
__global__ __launch_bounds__(256) void cvt_fused(const float* __restrict__ x,
                                                 const float* __restrict__ w,
                                                 short* __restrict__ xb,
                                                 short* __restrict__ wtb) {
    __shared__ float T[64][69];
    const int b = blockIdx.x;
    if (b < 2048) {
        const int i = (b * 256 + threadIdx.x) * 8;
        float4 a0 = ((const float4*)(x + i))[0];
        float4 a1 = ((const float4*)(x + i))[1];
        bf16x8 p;
        p[0]=f2bf(a0.x); p[1]=f2bf(a0.y); p[2]=f2bf(a0.z); p[3]=f2bf(a0.w);
        p[4]=f2bf(a1.x); p[5]=f2bf(a1.y); p[6]=f2bf(a1.z); p[7]=f2bf(a1.w);
        *(bf16x8*)(xb + i) = p;
        return;
    }
    const int bb = b - 2048;
    const int n0 = (bb % 48) * 64, k0 = (bb / 48) * 64;
    const int t = threadIdx.x;
    {
        const int kr = t >> 4, nc = (t & 15) * 4;
        #pragma unroll
        for (int i = 0; i < 4; ++i) {
            float4 v = *(const float4*)(w + (size_t)(k0 + kr + i * 16) * 3072 + n0 + nc);
            T[kr + i * 16][nc + 0] = v.x; T[kr + i * 16][nc + 1] = v.y;
            T[kr + i * 16][nc + 2] = v.z; T[kr + i * 16][nc + 3] = v.w;
        }
    }
    __syncthreads();
    const int nr = t >> 4, kc = (t & 15) * 4;
    #pragma unroll
    for (int i = 0; i < 4; ++i) {
        const int n = n0 + nr + i * 16;
        const float sc = (n >= 1024 && n < 2048) ? (LOG2E / 32.0f) : 1.0f;
        short4 o;
        o.x = f2bf(T[kc + 0][nr + i * 16] * sc);
        o.y = f2bf(T[kc + 1][nr + i * 16] * sc);
        o.z = f2bf(T[kc + 2][nr + i * 16] * sc);
        o.w = f2bf(T[kc + 3][nr + i * 16] * sc);
        *(short4*)(wtb + (size_t)n * 1024 + k0 + kc) = o;
    }
}

// ---- QKV GEMM (m97 structure): 128x128 tile, BK=64, global_load_lds.
//      V^T stored with keys tau-permuted within each 64-tile:
//      tau(32a+16b+4c+r) = 32a+8c+4b+r  (field swap), so attn's PV
//      B-fragment is one contiguous b128 per (ks,ldiv). ----
__global__ __launch_bounds__(256) void qkv_gemm(const short* __restrict__ xb,
                                                const short* __restrict__ wtb,
                                                short* __restrict__ kq,
                                                short* __restrict__ vt) {
    __shared__ short As[128 * 64];
    __shared__ short Bs[128 * 64];
    const int col0 = blockIdx.y * 128, row0 = blockIdx.x * 128;
    const int tid = threadIdx.x, w = tid >> 6, lane = tid & 63;
    const int lmod = lane & 15, ldiv = lane >> 4;
    const int wr = (w >> 1) * 64, wc = (w & 1) * 64;

    f32x4 acc[4][4] = {};
    const short* Ag = xb  + (size_t)row0 * DM;
    const short* Bg = wtb + (size_t)col0 * DM;

    for (int k0 = 0; k0 < DM; k0 += 64) {
        __syncthreads();
        #pragma unroll
        for (int t = 0; t < 4; ++t) {
            const int o = (w * 4 + t) * 1024 + lane * 16;
            const int r = o >> 7, cs = (o & 127) >> 1;
            load_lds16(Ag + (size_t)r * DM + k0 + cs, As + (w * 4 + t) * 512);
            load_lds16(Bg + (size_t)r * DM + k0 + cs, Bs + (w * 4 + t) * 512);
        }
        __syncthreads();
        #pragma unroll
        for (int ks = 0; ks < 2; ++ks) {
            bf16x8 af[4], bf[4];
            #pragma unroll
            for (int i = 0; i < 4; ++i)
                af[i] = *(const bf16x8*)(As + (wr + i * 16 + lmod) * 64 + ks * 32 + ldiv * 8);
            #pragma unroll
            for (int j = 0; j < 4; ++j)
                bf[j] = *(const bf16x8*)(Bs + (wc + j * 16 + lmod) * 64 + ks * 32 + ldiv * 8);
            #pragma unroll
            for (int i = 0; i < 4; ++i)
                #pragma unroll
                for (int j = 0; j < 4; ++j)
                    acc[i][j] = __builtin_amdgcn_mfma_f32_16x16x32_bf16(af[i], bf[j], acc[i][j], 0, 0, 0);
        }
    }

    if (col0 < 2048) {
        #pragma unroll
        for (int i = 0; i < 4; ++i)
            #pragma unroll
            for (int j = 0; j < 4; ++j)
                #pragma unroll
                for (int r = 0; r < 4; ++r)
                    kq[(size_t)(row0 + wr + i * 16 + ldiv * 4 + r) * 2048
                       + col0 + wc + j * 16 + lmod] = f2bf(acc[i][j][r]);
    } else {
        #pragma unroll
        for (int i = 0; i < 4; ++i) {
            const int ig = row0 + wr + i * 16 + ldiv * 4;
            const int kk = ig & 63;
            // tau: 32a+16b+4c -> 32a+8c+4b
            const int kkp = (kk & 32) | ((kk & 12) << 1) | ((kk & 16) >> 2);
            const int igp = (ig & ~63) | kkp;
            #pragma unroll
            for (int j = 0; j < 4; ++j) {
                const int cg = col0 + wc + j * 16 + lmod - 2048;
                const int h = cg >> 6, d = cg & 63;
                bf16x4 p;
                p[0]=f2bf(acc[i][j][0]); p[1]=f2bf(acc[i][j][1]);
                p[2]=f2bf(acc[i][j][2]); p[3]=f2bf(acc[i][j][3]);
                *(bf16x4*)(vt + (size_t)(h * 64 + d) * SEQ + igp) = p;
            }
        }
    }
}

// ---- flash attention, split-K 2-way.
//  v5 = v3 shell (single-buffer LDS, 2-barrier-per-tile staging — the config
//  that wins vs dbuf in BOTH A/Bs v1<->v2 and v3<->v4: global_load_lds into a
//  runtime-indexed buffer forces a conservative vmcnt(0) before compute's
//  ds_reads, serializing the loop) + v4 compute body (in-register softmax via
//  swapped QK^T; V pre-tau-permuted in vt so the PV B-fragment is one
//  conflict-free b128; cvt_pk packing; setprio around compute).
//  LDS 16KB -> thread-limited 8 blocks/CU possible. ----
__global__ __launch_bounds__(256, 4) void attn(const short* __restrict__ kq,
                                               const short* __restrict__ vt,
                                               float* __restrict__ o0,
                                               float* __restrict__ o1,
                                               float* __restrict__ ls0,
                                               float* __restrict__ ls1) {
    __shared__ short Ks[64 * 64];
    __shared__ short Vs[64 * 64];

    // band-interleaved decode: per-CU resident set sums to 66 units
    const int b = blockIdx.x;
    const int band = b >> 8, pos = b & 255, g = pos >> 5;
    const int qt = (band & 1) ? (24 - band * 8 + g) : (31 - band * 8 - g);
    const int h = (pos >> 1) & 15, s = pos & 1;

    const int tid = threadIdx.x, w = tid >> 6, lane = tid & 63;
    const int lmod = lane & 15, ldiv = lane >> 4;
    const float slope2 = exp2f(-0.5f * (float)(h + 1)) * LOG2E;

    // staging: wave w stages rows w*16..w*16+15 of both K and V tiles.
    // lane l -> row w*16 + (l>>3) (+8 for 2nd load), phys chunk l&7;
    // global logical chunk = phys ^ (row&7)  (swizzle on source address).
    const int sr0 = w * 16 + (lane >> 3), sr1 = sr0 + 8;
    const int sc0 = (lane & 7) ^ (sr0 & 7), sc1 = (lane & 7) ^ (sr1 & 7);

    const int xorm = lmod & 7;                 // read-side swizzle
    const int cxs0 = (ldiv ^ xorm) * 8;        // phys short offset, chunk ldiv
    const int cxs1 = ((4 + ldiv) ^ xorm) * 8;  // phys short offset, chunk 4+ldiv

    const int rowbase = qt * 128 + w * 32;

    // Q fragments (2 m-blocks x 2 d-chunks) — the MFMA B operand
    bf16x8 qf[2][2];
    #pragma unroll
    for (int m = 0; m < 2; ++m) {
        const short* qp = kq + (size_t)(rowbase + m * 16 + lmod) * 2048 + 1024 + h * 64;
        qf[m][0] = *(const bf16x8*)(qp + ldiv * 8);
        qf[m][1] = *(const bf16x8*)(qp + 32 + ldiv * 8);
    }
    // swapped layout: lane holds S[k = kt*64 + nt*16 + 4*ldiv + r][q = lmod]
    int db2[2];
    f32x4 pre4[2];
    #pragma unroll
    for (int m = 0; m < 2; ++m) {
        db2[m] = 4 * ldiv - (rowbase + m * 16 + lmod);
        #pragma unroll
        for (int r = 0; r < 4; ++r) pre4[m][r] = slope2 * (float)(db2[m] + r);
    }

    f32x4 O[2][4] = {};
    f32x4 ls4[2] = {};
    const int kt0 = s ? (qt + 1) : 0;
    const int kt1 = s ? (2 * qt + 2) : (qt + 1);

    for (int kt = kt0; kt < kt1; ++kt) {
        __syncthreads();   // prev compute done reading Ks/Vs
        {
            const short* kb = kq + (size_t)(kt * 64) * 2048 + h * 64;
            load_lds16(kb + (size_t)sr0 * 2048 + sc0 * 8, Ks + (w * 16) * 64);
            load_lds16(kb + (size_t)sr1 * 2048 + sc1 * 8, Ks + (w * 16 + 8) * 64);
            const short* vb = vt + (size_t)(h * 64) * SEQ + kt * 64;
            load_lds16(vb + (size_t)sr0 * SEQ + sc0 * 8, Vs + (w * 16) * 64);
            load_lds16(vb + (size_t)sr1 * SEQ + sc1 * 8, Vs + (w * 16 + 8) * 64);
        }
        __syncthreads();   // vmcnt drained -> LDS ready

        const bool diag = (kt >= 2 * qt);
        const int dt = kt * 64;
        const float cb = slope2 * (float)dt;

        __builtin_amdgcn_s_setprio(1);
        #pragma unroll
        for (int ks = 0; ks < 2; ++ks) {       // 32-key chunk for PV
            u32x4 pk0, pk1;
            #pragma unroll
            for (int j1 = 0; j1 < 2; ++j1) {   // K 16-row block nt = 2ks+j1
                const int nt = ks * 2 + j1;
                const float cn = cb + slope2 * (float)(nt * 16);
                f32x4 s0 = pre4[0] + cn;
                f32x4 s1 = pre4[1] + cn;
                const short* krow = Ks + (nt * 16 + lmod) * 64;
                const bf16x8 kf0 = *(const bf16x8*)(krow + cxs0);
                const bf16x8 kf1 = *(const bf16x8*)(krow + cxs1);
                s0 = __builtin_amdgcn_mfma_f32_16x16x32_bf16(kf0, qf[0][0], s0, 0, 0, 0);
                s0 = __builtin_amdgcn_mfma_f32_16x16x32_bf16(kf1, qf[0][1], s0, 0, 0, 0);
                s1 = __builtin_amdgcn_mfma_f32_16x16x32_bf16(kf0, qf[1][0], s1, 0, 0, 0);
                s1 = __builtin_amdgcn_mfma_f32_16x16x32_bf16(kf1, qf[1][1], s1, 0, 0, 0);

                f32x4 p0, p1;
                if (diag) {
                    #pragma unroll
                    for (int r = 0; r < 4; ++r) {
                        float v0 = s0[r], v1 = s1[r];
                        if (dt + nt * 16 + r + db2[0] > 0) v0 = -1e30f;
                        if (dt + nt * 16 + r + db2[1] > 0) v1 = -1e30f;
                        p0[r] = __builtin_amdgcn_exp2f(v0);
                        p1[r] = __builtin_amdgcn_exp2f(v1);
                    }
                } else {
                    #pragma unroll
                    for (int r = 0; r < 4; ++r) {
                        p0[r] = __builtin_amdgcn_exp2f(s0[r]);
                        p1[r] = __builtin_amdgcn_exp2f(s1[r]);
                    }
                }
                ls4[0] += p0;
                ls4[1] += p1;
                pk0[j1 * 2]     = cvtpk(p0[0], p0[1]);
                pk0[j1 * 2 + 1] = cvtpk(p0[2], p0[3]);
                pk1[j1 * 2]     = cvtpk(p1[0], p1[1]);
                pk1[j1 * 2 + 1] = cvtpk(p1[2], p1[3]);
            }
            const bf16x8 pa0 = __builtin_bit_cast(bf16x8, pk0);
            const bf16x8 pa1 = __builtin_bit_cast(bf16x8, pk1);
            const int cxo = ks ? cxs1 : cxs0;
            #pragma unroll
            for (int nt2 = 0; nt2 < 4; ++nt2) {
                const bf16x8 vf = *(const bf16x8*)(Vs + (nt2 * 16 + lmod) * 64 + cxo);
                O[0][nt2] = __builtin_amdgcn_mfma_f32_16x16x32_bf16(pa0, vf, O[0][nt2], 0, 0, 0);
                O[1][nt2] = __builtin_amdgcn_mfma_f32_16x16x32_bf16(pa1, vf, O[1][nt2], 0, 0, 0);
            }
        }
        __builtin_amdgcn_s_setprio(0);
    }

    // row sums: lane holds partial for q = lmod; reduce across ldiv groups
    float lsum[2];
    #pragma unroll
    for (int m = 0; m < 2; ++m) {
        float v = (ls4[m][0] + ls4[m][1]) + (ls4[m][2] + ls4[m][3]);
        v += __shfl_xor(v, 16);
        v += __shfl_xor(v, 32);
        lsum[m] = v;
    }

    float* ob = s ? o1 : o0;
    float* lb = s ? ls1 : ls0;
    #pragma unroll
    for (int m = 0; m < 2; ++m) {
        const int i0 = rowbase + m * 16 + ldiv * 4;
        #pragma unroll
        for (int nt2 = 0; nt2 < 4; ++nt2)
            #pragma unroll
            for (int r = 0; r < 4; ++r)
                ob[(size_t)(i0 + r) * DM + h * 64 + nt2 * 16 + lmod] = O[m][nt2][r];
    }
    if (ldiv == 0) {
        #pragma unroll
        for (int m = 0; m < 2; ++m)
            lb[h * SEQ + rowbase + m * 16 + lmod] = lsum[m];
    }
}

// ---- combine: out = (O0 + O1) / (l0 + l1) ----
__global__ __launch_bounds__(256) void combine(float* __restrict__ out,
                                               const float* __restrict__ opart,
                                               const float* __restrict__ ls0,
                                               const float* __restrict__ ls1) {
    const int i8 = (blockIdx.x * 256 + threadIdx.x) * 8;
    const int row = i8 >> 10, col = i8 & 1023, h = col >> 6;
    const float l = ls0[h * SEQ + row] + ls1[h * SEQ + row];
    const float rc = 1.0f / l;
    float4 a0 = *(const float4*)(out + i8);
    float4 a1 = *(const float4*)(out + i8 + 4);
    float4 b0 = *(const float4*)(opart + i8);
    float4 b1 = *(const float4*)(opart + i8 + 4);
    float4 c0, c1;
    c0.x = (a0.x + b0.x) * rc; c0.y = (a0.y + b0.y) * rc;
    c0.z = (a0.z + b0.z) * rc; c0.w = (a0.w + b0.w) * rc;
    c1.x = (a1.x + b1.x) * rc; c1.y = (a1.y + b1.y) * rc;
    c1.z = (a1.z + b1.z) * rc; c1.w = (a1.w + b1.w) * rc;
    *(float4*)(out + i8) = c0;
    *(float4*)(out + i8 + 4) = c1;
}

extern "C" void kernel_launch(void* const* d_in, const int* in_sizes, int n_in,
                              void* d_out, int out_size, void* d_ws, size_t ws_size,
                              hipStream_t stream) {
    const float* x = (const float*)d_in[0];   // [1,4096,1024] fp32
    const float* w = (const float*)d_in[1];   // [1024,3072] fp32
    float* out = (float*)d_out;

    char* ws = (char*)d_ws;
    short* kq    = (short*)(ws);                        // 16 MB: K|Q [4096][2048]
    short* vt    = (short*)(ws + ((size_t)16 << 20));   //  8 MB: V^T [16][64][4096] (tau-permuted keys)
    short* xb    = (short*)(ws + ((size_t)24 << 20));   //  8 MB: x bf16 (dead after gemm)
    short* wtb   = (short*)(ws + ((size_t)32 << 20));   //  6 MB: w^T bf16 (dead after gemm)
    float* opart = (float*)(ws + ((size_t)24 << 20));   // 16 MB: split-1 partial O (reuses xb/wtb)
    float* ls0   = (float*)(ws + ((size_t)40 << 20));   // 256 KB
    float* ls1   = (float*)(ws + ((size_t)40 << 20) + (256 << 10));

    cvt_fused<<<2048 + 768, 256, 0, stream>>>(x, w, xb, wtb);
    qkv_gemm <<<dim3(SEQ / 128, 3072 / 128), 256, 0, stream>>>(xb, wtb, kq, vt);
    attn     <<<1024, 256, 0, stream>>>(kq, vt, out, opart, ls0, ls1);
    combine  <<<SEQ * DM / (256 * 8), 256, 0, stream>>>(out, opart, ls0, ls1);
}

// Round 5
// 181.863 us; speedup vs baseline: 1.1813x; 1.1813x over previous
//
#include <hip/hip_runtime.h>
#include <stdint.h>
#include <math.h>

#define SEQ 4096
#define DM  1024
#define NH  16
#define DH  64
#define LOG2E 1.44269504088896341f

typedef short bf16x8 __attribute__((ext_vector_type(8)));
typedef short bf16x4 __attribute__((ext_vector_type(4)));
typedef float f32x4  __attribute__((ext_vector_type(4)));
typedef uint32_t u32x4 __attribute__((ext_vector_type(4)));

typedef const __attribute__((address_space(1))) short* gptr_t;
typedef __attribute__((address_space(3))) short* lptr_t;

__device__ __forceinline__ short f2bf(float f) {
    union { float f; uint32_t u; } x; x.f = f;
    uint32_t r = (x.u + 0x7fffu + ((x.u >> 16) & 1u)) >> 16;
    return (short)r;
}
__device__ __forceinline__ short f2bf_trunc(float f) {
    union { float f; uint32_t u; } x; x.f = f;
    return (short)(x.u >> 16);
}
// pack two f32 -> dword of two truncated bf16 (lo in low half) — plain bit
// ops, fully schedulable by the compiler (inline-asm cvt_pk measured -35%
// here, consistent with m240: opaque asm blocks exp2/pack <-> MFMA interleave)
__device__ __forceinline__ uint32_t pkbf(float lo, float hi) {
    union { float f; uint32_t u; } a, b; a.f = lo; b.f = hi;
    return (a.u >> 16) | (b.u & 0xffff0000u);
}

__device__ __forceinline__ void load_lds16(const short* g, const short* l) {
    __builtin_amdgcn_global_load_lds((gptr_t)(uintptr_t)g,
                                     (lptr_t)(uint32_t)(uintptr_t)l, 16, 0, 0);
}

// ---- fused prep: blocks [0,2048) convert x fp32->bf16; blocks [2048,2816)
//      transpose w [1024][3072] -> wtb [3072][1024] bf16, Q cols pre-scaled ----
__global__ __launch_bounds__(256) void cvt_fused(const float* __restrict__ x,
                                                 const float* __restrict__ w,
                                                 short* __restrict__ xb,
                                                 short* __restrict__ wtb) {
    __shared__ float T[64][69];
    const int b = blockIdx.x;
    if (b < 2048) {
        const int i = (b * 256 + threadIdx.x) * 8;
        float4 a0 = ((const float4*)(x + i))[0];
        float4 a1 = ((const float4*)(x + i))[1];
        bf16x8 p;
        p[0]=f2bf(a0.x); p[1]=f2bf(a0.y); p[2]=f2bf(a0.z); p[3]=f2bf(a0.w);
        p[4]=f2bf(a1.x); p[5]=f2bf(a1.y); p[6]=f2bf(a1.z); p[7]=f2bf(a1.w);
        *(bf16x8*)(xb + i) = p;
        return;
    }
    const int bb = b - 2048;
    const int n0 = (bb % 48) * 64, k0 = (bb / 48) * 64;
    const int t = threadIdx.x;
    {
        const int kr = t >> 4, nc = (t & 15) * 4;
        #pragma unroll
        for (int i = 0; i < 4; ++i) {
            float4 v = *(const float4*)(w + (size_t)(k0 + kr + i * 16) * 3072 + n0 + nc);
            T[kr + i * 16][nc + 0] = v.x; T[kr + i * 16][nc + 1] = v.y;
            T[kr + i * 16][nc + 2] = v.z; T[kr + i * 16][nc + 3] = v.w;
        }
    }
    __syncthreads();
    const int nr = t >> 4, kc = (t & 15) * 4;
    #pragma unroll
    for (int i = 0; i < 4; ++i) {
        const int n = n0 + nr + i * 16;
        const float sc = (n >= 1024 && n < 2048) ? (LOG2E / 32.0f) : 1.0f;
        short4 o;
        o.x = f2bf(T[kc + 0][nr + i * 16] * sc);
        o.y = f2bf(T[kc + 1][nr + i * 16] * sc);
        o.z = f2bf(T[kc + 2][nr + i * 16] * sc);
        o.w = f2bf(T[kc + 3][nr + i * 16] * sc);
        *(short4*)(wtb + (size_t)n * 1024 + k0 + kc) = o;
    }
}

// ---- QKV GEMM (m97 structure): 128x128 tile, BK=64, global_load_lds.
//      V^T stored with keys tau-permuted within each 64-tile:
//      tau(32a+16b+4c+r) = 32a+8c+4b+r  (field swap), so attn's PV
//      B-fragment is one contiguous conflict-free b128 per (ks,ldiv). ----
__global__ __launch_bounds__(256) void qkv_gemm(const short* __restrict__ xb,
                                                const short* __restrict__ wtb,
                                                short* __restrict__ kq,
                                                short* __restrict__ vt) {
    __shared__ short As[128 * 64];
    __shared__ short Bs[128 * 64];
    const int col0 = blockIdx.y * 128, row0 = blockIdx.x * 128;
    const int tid = threadIdx.x, w = tid >> 6, lane = tid & 63;
    const int lmod = lane & 15, ldiv = lane >> 4;
    const int wr = (w >> 1) * 64, wc = (w & 1) * 64;

    f32x4 acc[4][4] = {};
    const short* Ag = xb  + (size_t)row0 * DM;
    const short* Bg = wtb + (size_t)col0 * DM;

    for (int k0 = 0; k0 < DM; k0 += 64) {
        __syncthreads();
        #pragma unroll
        for (int t = 0; t < 4; ++t) {
            const int o = (w * 4 + t) * 1024 + lane * 16;
            const int r = o >> 7, cs = (o & 127) >> 1;
            load_lds16(Ag + (size_t)r * DM + k0 + cs, As + (w * 4 + t) * 512);
            load_lds16(Bg + (size_t)r * DM + k0 + cs, Bs + (w * 4 + t) * 512);
        }
        __syncthreads();
        #pragma unroll
        for (int ks = 0; ks < 2; ++ks) {
            bf16x8 af[4], bf[4];
            #pragma unroll
            for (int i = 0; i < 4; ++i)
                af[i] = *(const bf16x8*)(As + (wr + i * 16 + lmod) * 64 + ks * 32 + ldiv * 8);
            #pragma unroll
            for (int j = 0; j < 4; ++j)
                bf[j] = *(const bf16x8*)(Bs + (wc + j * 16 + lmod) * 64 + ks * 32 + ldiv * 8);
            #pragma unroll
            for (int i = 0; i < 4; ++i)
                #pragma unroll
                for (int j = 0; j < 4; ++j)
                    acc[i][j] = __builtin_amdgcn_mfma_f32_16x16x32_bf16(af[i], bf[j], acc[i][j], 0, 0, 0);
        }
    }

    if (col0 < 2048) {
        #pragma unroll
        for (int i = 0; i < 4; ++i)
            #pragma unroll
            for (int j = 0; j < 4; ++j)
                #pragma unroll
                for (int r = 0; r < 4; ++r)
                    kq[(size_t)(row0 + wr + i * 16 + ldiv * 4 + r) * 2048
                       + col0 + wc + j * 16 + lmod] = f2bf(acc[i][j][r]);
    } else {
        #pragma unroll
        for (int i = 0; i < 4; ++i) {
            const int ig = row0 + wr + i * 16 + ldiv * 4;
            const int kk = ig & 63;
            // tau: 32a+16b+4c -> 32a+8c+4b
            const int kkp = (kk & 32) | ((kk & 12) << 1) | ((kk & 16) >> 2);
            const int igp = (ig & ~63) | kkp;
            #pragma unroll
            for (int j = 0; j < 4; ++j) {
                const int cg = col0 + wc + j * 16 + lmod - 2048;
                const int h = cg >> 6, d = cg & 63;
                bf16x4 p;
                p[0]=f2bf(acc[i][j][0]); p[1]=f2bf(acc[i][j][1]);
                p[2]=f2bf(acc[i][j][2]); p[3]=f2bf(acc[i][j][3]);
                *(bf16x4*)(vt + (size_t)(h * 64 + d) * SEQ + igp) = p;
            }
        }
    }
}

// ---- flash attention, split-K 2-way.
//  v6 = v3 (best measured: single-buffer LDS, 2-barrier staging, pkbf
//  packing, no setprio, no inline asm in the loop) + ONLY the verified
//  conflict fix: V pre-tau-permuted in vt so the PV B-fragment is one
//  b128 at the proven conflict-free offsets (v4/v5: conflicts 4.3M -> 0).
//  One-variable A/B against v3. ----
__global__ __launch_bounds__(256, 4) void attn(const short* __restrict__ kq,
                                               const short* __restrict__ vt,
                                               float* __restrict__ o0,
                                               float* __restrict__ o1,
                                               float* __restrict__ ls0,
                                               float* __restrict__ ls1) {
    __shared__ short Ks[64 * 64];
    __shared__ short Vs[64 * 64];

    // band-interleaved decode: per-CU resident set sums to 66 units
    const int b = blockIdx.x;
    const int band = b >> 8, pos = b & 255, g = pos >> 5;
    const int qt = (band & 1) ? (24 - band * 8 + g) : (31 - band * 8 - g);
    const int h = (pos >> 1) & 15, s = pos & 1;

    const int tid = threadIdx.x, w = tid >> 6, lane = tid & 63;
    const int lmod = lane & 15, ldiv = lane >> 4;
    const float slope2 = exp2f(-0.5f * (float)(h + 1)) * LOG2E;

    // staging: wave w stages rows w*16..w*16+15 of both K and V tiles.
    // lane l -> row w*16 + (l>>3) (+8 for 2nd load), phys chunk l&7;
    // global logical chunk = phys ^ (row&7)  (swizzle on source address).
    const int sr0 = w * 16 + (lane >> 3), sr1 = sr0 + 8;
    const int sc0 = (lane & 7) ^ (sr0 & 7), sc1 = (lane & 7) ^ (sr1 & 7);

    const int xorm = lmod & 7;                 // read-side swizzle
    const int cxs0 = (ldiv ^ xorm) * 8;        // phys short offset, chunk ldiv
    const int cxs1 = ((4 + ldiv) ^ xorm) * 8;  // phys short offset, chunk 4+ldiv

    const int rowbase = qt * 128 + w * 32;

    // Q fragments (2 m-blocks x 2 d-chunks) — the MFMA B operand
    bf16x8 qf[2][2];
    #pragma unroll
    for (int m = 0; m < 2; ++m) {
        const short* qp = kq + (size_t)(rowbase + m * 16 + lmod) * 2048 + 1024 + h * 64;
        qf[m][0] = *(const bf16x8*)(qp + ldiv * 8);
        qf[m][1] = *(const bf16x8*)(qp + 32 + ldiv * 8);
    }
    // swapped layout: lane holds S[k = kt*64 + nt*16 + 4*ldiv + r][q = lmod]
    int db2[2];
    float pre[2][4];
    #pragma unroll
    for (int m = 0; m < 2; ++m) {
        db2[m] = 4 * ldiv - (rowbase + m * 16 + lmod);
        #pragma unroll
        for (int r = 0; r < 4; ++r) pre[m][r] = slope2 * (float)(db2[m] + r);
    }

    f32x4 O[2][4] = {};
    float lsum[2] = {};
    const int kt0 = s ? (qt + 1) : 0;
    const int kt1 = s ? (2 * qt + 2) : (qt + 1);

    for (int kt = kt0; kt < kt1; ++kt) {
        __syncthreads();   // prev compute done reading Ks/Vs
        {
            const short* kb = kq + (size_t)(kt * 64) * 2048 + h * 64;
            load_lds16(kb + (size_t)sr0 * 2048 + sc0 * 8, Ks + (w * 16) * 64);
            load_lds16(kb + (size_t)sr1 * 2048 + sc1 * 8, Ks + (w * 16 + 8) * 64);
            const short* vb = vt + (size_t)(h * 64) * SEQ + kt * 64;
            load_lds16(vb + (size_t)sr0 * SEQ + sc0 * 8, Vs + (w * 16) * 64);
            load_lds16(vb + (size_t)sr1 * SEQ + sc1 * 8, Vs + (w * 16 + 8) * 64);
        }
        __syncthreads();   // vmcnt drained -> LDS ready

        const bool diag = (kt >= 2 * qt);
        const int dt = kt * 64;
        const float cb = slope2 * (float)dt;

        #pragma unroll
        for (int ks = 0; ks < 2; ++ks) {       // 32-key chunk for PV
            u32x4 pk0, pk1;
            #pragma unroll
            for (int j1 = 0; j1 < 2; ++j1) {   // K 16-row block nt = 2ks+j1
                const int nt = ks * 2 + j1;
                const float cn = cb + slope2 * (float)(nt * 16);
                f32x4 s0, s1;
                #pragma unroll
                for (int r = 0; r < 4; ++r) { s0[r] = pre[0][r] + cn; s1[r] = pre[1][r] + cn; }
                const short* krow = Ks + (nt * 16 + lmod) * 64;
                const bf16x8 kf0 = *(const bf16x8*)(krow + cxs0);
                const bf16x8 kf1 = *(const bf16x8*)(krow + cxs1);
                s0 = __builtin_amdgcn_mfma_f32_16x16x32_bf16(kf0, qf[0][0], s0, 0, 0, 0);
                s0 = __builtin_amdgcn_mfma_f32_16x16x32_bf16(kf1, qf[0][1], s0, 0, 0, 0);
                s1 = __builtin_amdgcn_mfma_f32_16x16x32_bf16(kf0, qf[1][0], s1, 0, 0, 0);
                s1 = __builtin_amdgcn_mfma_f32_16x16x32_bf16(kf1, qf[1][1], s1, 0, 0, 0);

                float p0[4], p1[4];
                if (diag) {
                    #pragma unroll
                    for (int r = 0; r < 4; ++r) {
                        float v0 = s0[r], v1 = s1[r];
                        if (dt + nt * 16 + r + db2[0] > 0) v0 = -1e30f;
                        if (dt + nt * 16 + r + db2[1] > 0) v1 = -1e30f;
                        p0[r] = __builtin_amdgcn_exp2f(v0);
                        p1[r] = __builtin_amdgcn_exp2f(v1);
                    }
                } else {
                    #pragma unroll
                    for (int r = 0; r < 4; ++r) {
                        p0[r] = __builtin_amdgcn_exp2f(s0[r]);
                        p1[r] = __builtin_amdgcn_exp2f(s1[r]);
                    }
                }
                lsum[0] += (p0[0] + p0[1]) + (p0[2] + p0[3]);
                lsum[1] += (p1[0] + p1[1]) + (p1[2] + p1[3]);
                pk0[j1 * 2]     = pkbf(p0[0], p0[1]);
                pk0[j1 * 2 + 1] = pkbf(p0[2], p0[3]);
                pk1[j1 * 2]     = pkbf(p1[0], p1[1]);
                pk1[j1 * 2 + 1] = pkbf(p1[2], p1[3]);
            }
            const bf16x8 pa0 = __builtin_bit_cast(bf16x8, pk0);
            const bf16x8 pa1 = __builtin_bit_cast(bf16x8, pk1);
            const int cxo = ks ? cxs1 : cxs0;
            #pragma unroll
            for (int nt2 = 0; nt2 < 4; ++nt2) {
                const bf16x8 vf = *(const bf16x8*)(Vs + (nt2 * 16 + lmod) * 64 + cxo);
                O[0][nt2] = __builtin_amdgcn_mfma_f32_16x16x32_bf16(pa0, vf, O[0][nt2], 0, 0, 0);
                O[1][nt2] = __builtin_amdgcn_mfma_f32_16x16x32_bf16(pa1, vf, O[1][nt2], 0, 0, 0);
            }
        }
    }

    // row sums: lane holds partial for q = lmod; reduce across ldiv groups
    #pragma unroll
    for (int m = 0; m < 2; ++m) {
        float v = lsum[m];
        v += __shfl_xor(v, 16);
        v += __shfl_xor(v, 32);
        lsum[m] = v;
    }

    float* ob = s ? o1 : o0;
    float* lb = s ? ls1 : ls0;
    #pragma unroll
    for (int m = 0; m < 2; ++m) {
        const int i0 = rowbase + m * 16 + ldiv * 4;
        #pragma unroll
        for (int nt2 = 0; nt2 < 4; ++nt2)
            #pragma unroll
            for (int r = 0; r < 4; ++r)
                ob[(size_t)(i0 + r) * DM + h * 64 + nt2 * 16 + lmod] = O[m][nt2][r];
    }
    if (ldiv == 0) {
        #pragma unroll
        for (int m = 0; m < 2; ++m)
            lb[h * SEQ + rowbase + m * 16 + lmod] = lsum[m];
    }
}

// ---- combine: out = (O0 + O1) / (l0 + l1) ----
__global__ __launch_bounds__(256) void combine(float* __restrict__ out,
                                               const float* __restrict__ opart,
                                               const float* __restrict__ ls0,
                                               const float* __restrict__ ls1) {
    const int i8 = (blockIdx.x * 256 + threadIdx.x) * 8;
    const int row = i8 >> 10, col = i8 & 1023, h = col >> 6;
    const float l = ls0[h * SEQ + row] + ls1[h * SEQ + row];
    const float rc = 1.0f / l;
    float4 a0 = *(const float4*)(out + i8);
    float4 a1 = *(const float4*)(out + i8 + 4);
    float4 b0 = *(const float4*)(opart + i8);
    float4 b1 = *(const float4*)(opart + i8 + 4);
    float4 c0, c1;
    c0.x = (a0.x + b0.x) * rc; c0.y = (a0.y + b0.y) * rc;
    c0.z = (a0.z + b0.z) * rc; c0.w = (a0.w + b0.w) * rc;
    c1.x = (a1.x + b1.x) * rc; c1.y = (a1.y + b1.y) * rc;
    c1.z = (a1.z + b1.z) * rc; c1.w = (a1.w + b1.w) * rc;
    *(float4*)(out + i8) = c0;
    *(float4*)(out + i8 + 4) = c1;
}

extern "C" void kernel_launch(void* const* d_in, const int* in_sizes, int n_in,
                              void* d_out, int out_size, void* d_ws, size_t ws_size,
                              hipStream_t stream) {
    const float* x = (const float*)d_in[0];   // [1,4096,1024] fp32
    const float* w = (const float*)d_in[1];   // [1024,3072] fp32
    float* out = (float*)d_out;

    char* ws = (char*)d_ws;
    short* kq    = (short*)(ws);                        // 16 MB: K|Q [4096][2048]
    short* vt    = (short*)(ws + ((size_t)16 << 20));   //  8 MB: V^T [16][64][4096] (tau-permuted keys)
    short* xb    = (short*)(ws + ((size_t)24 << 20));   //  8 MB: x bf16 (dead after gemm)
    short* wtb   = (short*)(ws + ((size_t)32 << 20));   //  6 MB: w^T bf16 (dead after gemm)
    float* opart = (float*)(ws + ((size_t)24 << 20));   // 16 MB: split-1 partial O (reuses xb/wtb)
    float* ls0   = (float*)(ws + ((size_t)40 << 20));   // 256 KB
    float* ls1   = (float*)(ws + ((size_t)40 << 20) + (256 << 10));

    cvt_fused<<<2048 + 768, 256, 0, stream>>>(x, w, xb, wtb);
    qkv_gemm <<<dim3(SEQ / 128, 3072 / 128), 256, 0, stream>>>(xb, wtb, kq, vt);
    attn     <<<1024, 256, 0, stream>>>(kq, vt, out, opart, ls0, ls1);
    combine  <<<SEQ * DM / (256 * 8), 256, 0, stream>>>(out, opart, ls0, ls1);
}

// Round 6
// 160.272 us; speedup vs baseline: 1.3404x; 1.1347x over previous
//
#include <hip/hip_runtime.h>
#include <stdint.h>
#include <math.h>

#define SEQ 4096
#define DM  1024
#define NH  16
#define DH  64
#define LOG2E 1.44269504088896341f

typedef short bf16x8 __attribute__((ext_vector_type(8)));
typedef short bf16x4 __attribute__((ext_vector_type(4)));
typedef float f32x4  __attribute__((ext_vector_type(4)));
typedef uint32_t u32x4 __attribute__((ext_vector_type(4)));

typedef const __attribute__((address_space(1))) short* gptr_t;
typedef __attribute__((address_space(3))) short* lptr_t;

__device__ __forceinline__ short f2bf(float f) {
    union { float f; uint32_t u; } x; x.f = f;
    uint32_t r = (x.u + 0x7fffu + ((x.u >> 16) & 1u)) >> 16;
    return (short)r;
}
// pack two f32 -> dword of two truncated bf16 (lo in low half) — plain bit
// ops, fully schedulable (inline-asm cvt_pk measured -35% here; m240)
__device__ __forceinline__ uint32_t pkbf(float lo, float hi) {
    union { float f; uint32_t u; } a, b; a.f = lo; b.f = hi;
    return (a.u >> 16) | (b.u & 0xffff0000u);
}

__device__ __forceinline__ void load_lds16(const short* g, const short* l) {
    __builtin_amdgcn_global_load_lds((gptr_t)(uintptr_t)g,
                                     (lptr_t)(uint32_t)(uintptr_t)l, 16, 0, 0);
}

// raw workgroup barrier with compiler memory fence (no vmcnt auto-drain)
__device__ __forceinline__ void wgbar() {
    asm volatile("" ::: "memory");
    __builtin_amdgcn_s_barrier();
    asm volatile("" ::: "memory");
}
#define WAITVM(n) asm volatile("s_waitcnt vmcnt(" #n ")" ::: "memory")
#define DSR(d, a, o) asm volatile("ds_read_b128 %0, %1 offset:" o : "=v"(d) : "v"(a))

// ---- fused prep: blocks [0,2048) convert x fp32->bf16; blocks [2048,2816)
//      transpose w [1024][3072] -> wtb [3072][1024] bf16, Q cols pre-scaled ----
__global__ __launch_bounds__(256) void cvt_fused(const float* __restrict__ x,
                                                 const float* __restrict__ w,
                                                 short* __restrict__ xb,
                                                 short* __restrict__ wtb) {
    __shared__ float T[64][69];
    const int b = blockIdx.x;
    if (b < 2048) {
        const int i = (b * 256 + threadIdx.x) * 8;
        float4 a0 = ((const float4*)(x + i))[0];
        float4 a1 = ((const float4*)(x + i))[1];
        bf16x8 p;
        p[0]=f2bf(a0.x); p[1]=f2bf(a0.y); p[2]=f2bf(a0.z); p[3]=f2bf(a0.w);
        p[4]=f2bf(a1.x); p[5]=f2bf(a1.y); p[6]=f2bf(a1.z); p[7]=f2bf(a1.w);
        *(bf16x8*)(xb + i) = p;
        return;
    }
    const int bb = b - 2048;
    const int n0 = (bb % 48) * 64, k0 = (bb / 48) * 64;
    const int t = threadIdx.x;
    {
        const int kr = t >> 4, nc = (t & 15) * 4;
        #pragma unroll
        for (int i = 0; i < 4; ++i) {
            float4 v = *(const float4*)(w + (size_t)(k0 + kr + i * 16) * 3072 + n0 + nc);
            T[kr + i * 16][nc + 0] = v.x; T[kr + i * 16][nc + 1] = v.y;
            T[kr + i * 16][nc + 2] = v.z; T[kr + i * 16][nc + 3] = v.w;
        }
    }
    __syncthreads();
    const int nr = t >> 4, kc = (t & 15) * 4;
    #pragma unroll
    for (int i = 0; i < 4; ++i) {
        const int n = n0 + nr + i * 16;
        const float sc = (n >= 1024 && n < 2048) ? (LOG2E / 32.0f) : 1.0f;
        short4 o;
        o.x = f2bf(T[kc + 0][nr + i * 16] * sc);
        o.y = f2bf(T[kc + 1][nr + i * 16] * sc);
        o.z = f2bf(T[kc + 2][nr + i * 16] * sc);
        o.w = f2bf(T[kc + 3][nr + i * 16] * sc);
        *(short4*)(wtb + (size_t)n * 1024 + k0 + kc) = o;
    }
}

// ---- QKV GEMM v7: 128x128 tile, BK=64, distance-2 prefetch with counted
//      vmcnt(8) + raw barriers (no vmcnt(0) drain in steady state), XOR-8
//      swizzled LDS (pre-swizzled global source, proven 0-conflict pattern),
//      inline-asm ds_read_b128 so the compiler cannot insert conservative
//      drains. Epilogue identical to v6 (kq + tau-permuted vt). ----
__global__ __launch_bounds__(256, 2) void qkv_gemm(const short* __restrict__ xb,
                                                   const short* __restrict__ wtb,
                                                   short* __restrict__ kq,
                                                   short* __restrict__ vt) {
    __shared__ short As[2][8192];
    __shared__ short Bs[2][8192];
    const int col0 = blockIdx.y * 128, row0 = blockIdx.x * 128;
    const int tid = threadIdx.x, w = tid >> 6, lane = tid & 63;
    const int lmod = lane & 15, ldiv = lane >> 4;
    const int wr = (w >> 1) * 64, wc = (w & 1) * 64;

    // staging: wave w stages rows [w*32, w*32+32) of both tiles (4 issues).
    // linear LDS dest chunk c = w*256+q*64+lane; row=c>>3, phys chunk=lane&7,
    // logical (global) chunk = phys ^ (row&7) — swizzle on source address.
    const int srow = w * 32 + (lane >> 3);
    const int slc  = (lane & 7) ^ ((lane >> 3) & 7);
    const short* gA = xb  + (size_t)(row0 + srow) * 1024 + slc * 8;
    const short* gB = wtb + (size_t)(col0 + srow) * 1024 + slc * 8;
    short* lA = &As[0][0] + w * 2048;
    short* lB = &Bs[0][0] + w * 2048;

    // read-side: byte addr = base + row*128 + ((chunk ^ (row&7))*16);
    // row&7 == lmod&7 for all fragments; ks=1 toggles chunk bit2 -> addr^64.
    const uint32_t asb = (uint32_t)(uintptr_t)&As[0][0];
    const uint32_t bsb = (uint32_t)(uintptr_t)&Bs[0][0];
    const int xorm = lmod & 7;
    const int rdA = (wr + lmod) * 128 + ((ldiv ^ xorm) << 4);
    const int rdB = (wc + lmod) * 128 + ((ldiv ^ xorm) << 4);

    f32x4 acc[4][4] = {};

    auto stage = [&](int kt, int p) {
        const short* ga = gA + kt * 64;
        const short* gb = gB + kt * 64;
        short* la = lA + p * 8192;
        short* lb = lB + p * 8192;
        #pragma unroll
        for (int q = 0; q < 4; ++q) {
            load_lds16(ga + q * 8192, la + q * 512);
            load_lds16(gb + q * 8192, lb + q * 512);
        }
    };

    stage(0, 0);                 // 8 loads
    stage(1, 1);                 // 8 loads
    WAITVM(8);                   // tile 0 resident (own 8 oldest)
    wgbar();

    for (int t = 0; t < 16; ++t) {
        const int poff = (t & 1) << 14;
        const int aA0 = (int)asb + poff + rdA, aA1 = aA0 ^ 64;
        const int bA0 = (int)bsb + poff + rdB, bA1 = bA0 ^ 64;
        bf16x8 a0[4], a1[4], b0[4], b1[4];
        DSR(a0[0], aA0, "0");    DSR(a0[1], aA0, "2048");
        DSR(a0[2], aA0, "4096"); DSR(a0[3], aA0, "6144");
        DSR(b0[0], bA0, "0");    DSR(b0[1], bA0, "2048");
        DSR(b0[2], bA0, "4096"); DSR(b0[3], bA0, "6144");
        DSR(a1[0], aA1, "0");    DSR(a1[1], aA1, "2048");
        DSR(a1[2], aA1, "4096"); DSR(a1[3], aA1, "6144");
        DSR(b1[0], bA1, "0");    DSR(b1[1], bA1, "2048");
        DSR(b1[2], bA1, "4096"); DSR(b1[3], bA1, "6144");
        asm volatile("s_waitcnt lgkmcnt(8)" ::: "memory");   // ks=0 frags ready
        __builtin_amdgcn_sched_barrier(0);
        #pragma unroll
        for (int i = 0; i < 4; ++i)
            #pragma unroll
            for (int j = 0; j < 4; ++j)
                acc[i][j] = __builtin_amdgcn_mfma_f32_16x16x32_bf16(a0[i], b0[j], acc[i][j], 0, 0, 0);
        asm volatile("s_waitcnt lgkmcnt(0)" ::: "memory");   // ks=1 frags ready
        __builtin_amdgcn_sched_barrier(0);
        #pragma unroll
        for (int i = 0; i < 4; ++i)
            #pragma unroll
            for (int j = 0; j < 4; ++j)
                acc[i][j] = __builtin_amdgcn_mfma_f32_16x16x32_bf16(a1[i], b1[j], acc[i][j], 0, 0, 0);

        wgbar();                           // all waves done reading buf (t&1)
        if (t + 2 < 16) {
            stage(t + 2, t & 1);           // refill freed buffer (8 loads)
            WAITVM(8);                     // own tile-(t+1) loads complete
            wgbar();                       // everyone's tile-(t+1) resident
        } else if (t + 1 < 16) {
            WAITVM(0);                     // last tile: drain
            wgbar();
        }
    }

    if (col0 < 2048) {
        #pragma unroll
        for (int i = 0; i < 4; ++i)
            #pragma unroll
            for (int j = 0; j < 4; ++j)
                #pragma unroll
                for (int r = 0; r < 4; ++r)
                    kq[(size_t)(row0 + wr + i * 16 + ldiv * 4 + r) * 2048
                       + col0 + wc + j * 16 + lmod] = f2bf(acc[i][j][r]);
    } else {
        #pragma unroll
        for (int i = 0; i < 4; ++i) {
            const int ig = row0 + wr + i * 16 + ldiv * 4;
            const int kk = ig & 63;
            // tau: 32a+16b+4c -> 32a+8c+4b
            const int kkp = (kk & 32) | ((kk & 12) << 1) | ((kk & 16) >> 2);
            const int igp = (ig & ~63) | kkp;
            #pragma unroll
            for (int j = 0; j < 4; ++j) {
                const int cg = col0 + wc + j * 16 + lmod - 2048;
                const int h = cg >> 6, d = cg & 63;
                bf16x4 p;
                p[0]=f2bf(acc[i][j][0]); p[1]=f2bf(acc[i][j][1]);
                p[2]=f2bf(acc[i][j][2]); p[3]=f2bf(acc[i][j][3]);
                *(bf16x4*)(vt + (size_t)(h * 64 + d) * SEQ + igp) = p;
            }
        }
    }
}

// ---- flash attention, split-K 2-way (v6 — unchanged best). ----
__global__ __launch_bounds__(256, 4) void attn(const short* __restrict__ kq,
                                               const short* __restrict__ vt,
                                               float* __restrict__ o0,
                                               float* __restrict__ o1,
                                               float* __restrict__ ls0,
                                               float* __restrict__ ls1) {
    __shared__ short Ks[64 * 64];
    __shared__ short Vs[64 * 64];

    // band-interleaved decode: per-CU resident set sums to 66 units
    const int b = blockIdx.x;
    const int band = b >> 8, pos = b & 255, g = pos >> 5;
    const int qt = (band & 1) ? (24 - band * 8 + g) : (31 - band * 8 - g);
    const int h = (pos >> 1) & 15, s = pos & 1;

    const int tid = threadIdx.x, w = tid >> 6, lane = tid & 63;
    const int lmod = lane & 15, ldiv = lane >> 4;
    const float slope2 = exp2f(-0.5f * (float)(h + 1)) * LOG2E;

    const int sr0 = w * 16 + (lane >> 3), sr1 = sr0 + 8;
    const int sc0 = (lane & 7) ^ (sr0 & 7), sc1 = (lane & 7) ^ (sr1 & 7);

    const int xorm = lmod & 7;                 // read-side swizzle
    const int cxs0 = (ldiv ^ xorm) * 8;        // phys short offset, chunk ldiv
    const int cxs1 = ((4 + ldiv) ^ xorm) * 8;  // phys short offset, chunk 4+ldiv

    const int rowbase = qt * 128 + w * 32;

    bf16x8 qf[2][2];
    #pragma unroll
    for (int m = 0; m < 2; ++m) {
        const short* qp = kq + (size_t)(rowbase + m * 16 + lmod) * 2048 + 1024 + h * 64;
        qf[m][0] = *(const bf16x8*)(qp + ldiv * 8);
        qf[m][1] = *(const bf16x8*)(qp + 32 + ldiv * 8);
    }
    int db2[2];
    float pre[2][4];
    #pragma unroll
    for (int m = 0; m < 2; ++m) {
        db2[m] = 4 * ldiv - (rowbase + m * 16 + lmod);
        #pragma unroll
        for (int r = 0; r < 4; ++r) pre[m][r] = slope2 * (float)(db2[m] + r);
    }

    f32x4 O[2][4] = {};
    float lsum[2] = {};
    const int kt0 = s ? (qt + 1) : 0;
    const int kt1 = s ? (2 * qt + 2) : (qt + 1);

    for (int kt = kt0; kt < kt1; ++kt) {
        __syncthreads();
        {
            const short* kb = kq + (size_t)(kt * 64) * 2048 + h * 64;
            load_lds16(kb + (size_t)sr0 * 2048 + sc0 * 8, Ks + (w * 16) * 64);
            load_lds16(kb + (size_t)sr1 * 2048 + sc1 * 8, Ks + (w * 16 + 8) * 64);
            const short* vb = vt + (size_t)(h * 64) * SEQ + kt * 64;
            load_lds16(vb + (size_t)sr0 * SEQ + sc0 * 8, Vs + (w * 16) * 64);
            load_lds16(vb + (size_t)sr1 * SEQ + sc1 * 8, Vs + (w * 16 + 8) * 64);
        }
        __syncthreads();

        const bool diag = (kt >= 2 * qt);
        const int dt = kt * 64;
        const float cb = slope2 * (float)dt;

        #pragma unroll
        for (int ks = 0; ks < 2; ++ks) {
            u32x4 pk0, pk1;
            #pragma unroll
            for (int j1 = 0; j1 < 2; ++j1) {
                const int nt = ks * 2 + j1;
                const float cn = cb + slope2 * (float)(nt * 16);
                f32x4 s0, s1;
                #pragma unroll
                for (int r = 0; r < 4; ++r) { s0[r] = pre[0][r] + cn; s1[r] = pre[1][r] + cn; }
                const short* krow = Ks + (nt * 16 + lmod) * 64;
                const bf16x8 kf0 = *(const bf16x8*)(krow + cxs0);
                const bf16x8 kf1 = *(const bf16x8*)(krow + cxs1);
                s0 = __builtin_amdgcn_mfma_f32_16x16x32_bf16(kf0, qf[0][0], s0, 0, 0, 0);
                s0 = __builtin_amdgcn_mfma_f32_16x16x32_bf16(kf1, qf[0][1], s0, 0, 0, 0);
                s1 = __builtin_amdgcn_mfma_f32_16x16x32_bf16(kf0, qf[1][0], s1, 0, 0, 0);
                s1 = __builtin_amdgcn_mfma_f32_16x16x32_bf16(kf1, qf[1][1], s1, 0, 0, 0);

                float p0[4], p1[4];
                if (diag) {
                    #pragma unroll
                    for (int r = 0; r < 4; ++r) {
                        float v0 = s0[r], v1 = s1[r];
                        if (dt + nt * 16 + r + db2[0] > 0) v0 = -1e30f;
                        if (dt + nt * 16 + r + db2[1] > 0) v1 = -1e30f;
                        p0[r] = __builtin_amdgcn_exp2f(v0);
                        p1[r] = __builtin_amdgcn_exp2f(v1);
                    }
                } else {
                    #pragma unroll
                    for (int r = 0; r < 4; ++r) {
                        p0[r] = __builtin_amdgcn_exp2f(s0[r]);
                        p1[r] = __builtin_amdgcn_exp2f(s1[r]);
                    }
                }
                lsum[0] += (p0[0] + p0[1]) + (p0[2] + p0[3]);
                lsum[1] += (p1[0] + p1[1]) + (p1[2] + p1[3]);
                pk0[j1 * 2]     = pkbf(p0[0], p0[1]);
                pk0[j1 * 2 + 1] = pkbf(p0[2], p0[3]);
                pk1[j1 * 2]     = pkbf(p1[0], p1[1]);
                pk1[j1 * 2 + 1] = pkbf(p1[2], p1[3]);
            }
            const bf16x8 pa0 = __builtin_bit_cast(bf16x8, pk0);
            const bf16x8 pa1 = __builtin_bit_cast(bf16x8, pk1);
            const int cxo = ks ? cxs1 : cxs0;
            #pragma unroll
            for (int nt2 = 0; nt2 < 4; ++nt2) {
                const bf16x8 vf = *(const bf16x8*)(Vs + (nt2 * 16 + lmod) * 64 + cxo);
                O[0][nt2] = __builtin_amdgcn_mfma_f32_16x16x32_bf16(pa0, vf, O[0][nt2], 0, 0, 0);
                O[1][nt2] = __builtin_amdgcn_mfma_f32_16x16x32_bf16(pa1, vf, O[1][nt2], 0, 0, 0);
            }
        }
    }

    #pragma unroll
    for (int m = 0; m < 2; ++m) {
        float v = lsum[m];
        v += __shfl_xor(v, 16);
        v += __shfl_xor(v, 32);
        lsum[m] = v;
    }

    float* ob = s ? o1 : o0;
    float* lb = s ? ls1 : ls0;
    #pragma unroll
    for (int m = 0; m < 2; ++m) {
        const int i0 = rowbase + m * 16 + ldiv * 4;
        #pragma unroll
        for (int nt2 = 0; nt2 < 4; ++nt2)
            #pragma unroll
            for (int r = 0; r < 4; ++r)
                ob[(size_t)(i0 + r) * DM + h * 64 + nt2 * 16 + lmod] = O[m][nt2][r];
    }
    if (ldiv == 0) {
        #pragma unroll
        for (int m = 0; m < 2; ++m)
            lb[h * SEQ + rowbase + m * 16 + lmod] = lsum[m];
    }
}

// ---- combine: out = (O0 + O1) / (l0 + l1) ----
__global__ __launch_bounds__(256) void combine(float* __restrict__ out,
                                               const float* __restrict__ opart,
                                               const float* __restrict__ ls0,
                                               const float* __restrict__ ls1) {
    const int i8 = (blockIdx.x * 256 + threadIdx.x) * 8;
    const int row = i8 >> 10, col = i8 & 1023, h = col >> 6;
    const float l = ls0[h * SEQ + row] + ls1[h * SEQ + row];
    const float rc = 1.0f / l;
    float4 a0 = *(const float4*)(out + i8);
    float4 a1 = *(const float4*)(out + i8 + 4);
    float4 b0 = *(const float4*)(opart + i8);
    float4 b1 = *(const float4*)(opart + i8 + 4);
    float4 c0, c1;
    c0.x = (a0.x + b0.x) * rc; c0.y = (a0.y + b0.y) * rc;
    c0.z = (a0.z + b0.z) * rc; c0.w = (a0.w + b0.w) * rc;
    c1.x = (a1.x + b1.x) * rc; c1.y = (a1.y + b1.y) * rc;
    c1.z = (a1.z + b1.z) * rc; c1.w = (a1.w + b1.w) * rc;
    *(float4*)(out + i8) = c0;
    *(float4*)(out + i8 + 4) = c1;
}

extern "C" void kernel_launch(void* const* d_in, const int* in_sizes, int n_in,
                              void* d_out, int out_size, void* d_ws, size_t ws_size,
                              hipStream_t stream) {
    const float* x = (const float*)d_in[0];   // [1,4096,1024] fp32
    const float* w = (const float*)d_in[1];   // [1024,3072] fp32
    float* out = (float*)d_out;

    char* ws = (char*)d_ws;
    short* kq    = (short*)(ws);                        // 16 MB: K|Q [4096][2048]
    short* vt    = (short*)(ws + ((size_t)16 << 20));   //  8 MB: V^T [16][64][4096] (tau-permuted keys)
    short* xb    = (short*)(ws + ((size_t)24 << 20));   //  8 MB: x bf16 (dead after gemm)
    short* wtb   = (short*)(ws + ((size_t)32 << 20));   //  6 MB: w^T bf16 (dead after gemm)
    float* opart = (float*)(ws + ((size_t)24 << 20));   // 16 MB: split-1 partial O (reuses xb/wtb)
    float* ls0   = (float*)(ws + ((size_t)40 << 20));   // 256 KB
    float* ls1   = (float*)(ws + ((size_t)40 << 20) + (256 << 10));

    cvt_fused<<<2048 + 768, 256, 0, stream>>>(x, w, xb, wtb);
    qkv_gemm <<<dim3(SEQ / 128, 3072 / 128), 256, 0, stream>>>(xb, wtb, kq, vt);
    attn     <<<1024, 256, 0, stream>>>(kq, vt, out, opart, ls0, ls1);
    combine  <<<SEQ * DM / (256 * 8), 256, 0, stream>>>(out, opart, ls0, ls1);
}